// Round 3
// baseline (354013.745 us; speedup 1.0000x reference)
//
#include <hip/hip_runtime.h>

#define AGENT __HIP_MEMORY_SCOPE_AGENT
typedef unsigned int u32;
typedef unsigned long long u64;

constexpr int TSTEPS = 16384;
constexpr float INV_BINS    = 1.0f / 127.5f;
constexpr float INIT_SCALED = 128.0f * (1.0f / 127.5f) - 1.0f;

// ---- workspace byte offsets ------------------------------------------------
constexpr int AM_OFF   = 0;      // u64 slots: idx ((half*2+par)*8 + slot)*8   (64B/slot, 2 KiB)
constexpr int HEP_OFF  = 2048;   // u32 epochs: idx (par*2+half)*16            (64B apart)
constexpr int HPEP_OFF = 2304;   // u32 epochs: idx (half*2+par)*28 + wgl
constexpr int HBUF_OFF = 2816;   // f32: idx par*896 + i
constexpr int HP_OFF   = 9984;   // f32: idx (half*2+par)*1344 + i
constexpr int PRE_OFF  = 31488;  // u64 tagged: idx (half*2+par)*448 + i       (end ~45.8 KiB)

__device__ __forceinline__ u32  ld32a(const u32* p) { return __hip_atomic_load((u32*)p, __ATOMIC_ACQUIRE, AGENT); }
__device__ __forceinline__ void st32r(u32* p, u32 v){ __hip_atomic_store(p, v, __ATOMIC_RELEASE, AGENT); }
__device__ __forceinline__ float ldf(const float* p){ return __hip_atomic_load((float*)p, __ATOMIC_RELAXED, AGENT); }
__device__ __forceinline__ void  stf(float* p, float v){ __hip_atomic_store(p, v, __ATOMIC_RELAXED, AGENT); }
__device__ __forceinline__ u64  ld64(const u64* p){ return __hip_atomic_load((u64*)p, __ATOMIC_RELAXED, AGENT); }
__device__ __forceinline__ void st64(u64* p, u64 v){ __hip_atomic_store(p, v, __ATOMIC_RELAXED, AGENT); }

__device__ __forceinline__ float wave_sum(float s) {
  #pragma unroll
  for (int d = 1; d < 64; d <<= 1) s += __shfl_xor(s, d, 64);
  return s;
}
__device__ __forceinline__ float sigf(float x) { return 1.0f / (1.0f + __expf(-x)); }
__device__ __forceinline__ u64 u64max(u64 a, u64 b) { return a > b ? a : b; }
// packed argmax slot: [key:32 | tag:16 | 255-row:8]
__device__ __forceinline__ u64 pack_key(float x, int row, unsigned tag) {
  unsigned u = __float_as_uint(x);
  u = (u & 0x80000000u) ? ~u : (u | 0x80000000u);
  return ((u64)u << 32) | ((u64)(tag & 0xFFFFu) << 8) | (unsigned)(255 - row);
}
__device__ __forceinline__ int   slot_bin(u64 v)    { return 255 - (int)(v & 0xFFull); }
__device__ __forceinline__ float slot_scaled(u64 v) { return (float)slot_bin(v) * INV_BINS - 1.0f; }
__device__ __forceinline__ u64 red8(u64 rv) {
  #pragma unroll
  for (int d = 1; d < 8; d <<= 1) rv = u64max(rv, __shfl_xor(rv, d, 64));
  return rv;
}

extern "C" __global__ void __launch_bounds__(256, 1)
wavernn_persist(const float* __restrict__ Wh,  const float* __restrict__ bh,
                const float* __restrict__ Wci, const float* __restrict__ Wfi,
                const float* __restrict__ cbias, const float* __restrict__ fbias,
                const float* __restrict__ pWc, const float* __restrict__ pBc,
                const float* __restrict__ bWc, const float* __restrict__ bBc,
                const float* __restrict__ pWf, const float* __restrict__ pBf,
                const float* __restrict__ bWf, const float* __restrict__ bBf,
                const float* __restrict__ h0,
                float* __restrict__ out, char* __restrict__ wsb)
{
  const int tid  = threadIdx.x;
  const int lane = tid & 63;
  const int wv   = tid >> 6;
  const int wg   = blockIdx.x;

  u64* AMb   = (u64*)(wsb + AM_OFF);
  u32* HEPb  = (u32*)(wsb + HEP_OFF);
  u32* HPEPb = (u32*)(wsb + HPEP_OFF);
  float* HBUFb = (float*)(wsb + HBUF_OFF);
  float* HPb   = (float*)(wsb + HP_OFF);
  u64* PREb    = (u64*)(wsb + PRE_OFF);

  if (wg < 16) {
    // =================== output WGs: coarse 0-7, fine 8-15 ==================
    const int half = wg >> 3;
    const int oid  = wg & 7;
    const int ncol = half ? 3 : 2;
    const float* Wi  = half ? Wfi : Wci;
    const float* tbp = half ? fbias : cbias;
    const float* pW  = half ? pWf : pWc;
    const float* pB  = half ? pBf : pBc;
    const float* bW  = half ? bWf : bWc;
    const float* bB  = half ? bBf : bBc;

    const int u1 = tid;                 // gate unit 1 (0..255)
    const bool hasB = (tid < 192);
    const int u2 = 256 + tid;           // gate unit 2 (256..447)

    float wiA[3][3], wiB[3][3];
    #pragma unroll
    for (int g = 0; g < 3; ++g)
      #pragma unroll
      for (int c = 0; c < 3; ++c) {
        wiA[g][c] = (c < ncol) ? Wi[(g * 448 + u1) * ncol + c] : 0.0f;
        wiB[g][c] = (hasB && c < ncol) ? Wi[(g * 448 + u2) * ncol + c] : 0.0f;
      }
    float hvA = h0[half * 448 + u1];
    float hvB = hasB ? h0[half * 448 + u2] : 0.0f;

    const int wl = oid * 4 + wv;        // 0..31
    float wpre[14][7], bpre[14], wbin[8][7], bbin[8];
    #pragma unroll
    for (int r = 0; r < 14; ++r) {
      const int row = wl * 14 + r;
      #pragma unroll
      for (int k = 0; k < 7; ++k) wpre[r][k] = pW[row * 448 + k * 64 + lane];
      bpre[r] = pB[row];
    }
    #pragma unroll
    for (int r = 0; r < 8; ++r) {
      const int row = wl * 8 + r;
      #pragma unroll
      for (int k = 0; k < 7; ++k) wbin[r][k] = bW[row * 448 + k * 64 + lane];
      bbin[r] = bB[row];
    }

    __shared__ float sh[448];
    __shared__ u64 sm[4];

    for (int t = 0; t < TSTEPS; ++t) {
      const int par = t & 1, parp = par ^ 1;
      const unsigned tg = (unsigned)(t + 1);

      // stream per-step biases early (hide HBM latency under polls)
      float tbA[3], tbB[3];
      #pragma unroll
      for (int g = 0; g < 3; ++g) {
        tbA[g] = tbp[(size_t)t * 1344 + g * 448 + u1];
        tbB[g] = hasB ? tbp[(size_t)t * 1344 + g * 448 + u2] : 0.0f;
      }

      float c_prev = INIT_SCALED, f_prev = INIT_SCALED, csc = 0.0f;
      u64 rvf = 0;

      if (!half) {
        // ---- early: c(t-1) slots (tag t) --------------------------------
        if (t >= 1) {
          u64* amc = AMb + (size_t)(parp * 8) * 8;
          u64 rv = 0;
          for (;;) {
            bool ok = true;
            if (lane < 8) { rv = ld64(amc + lane * 8); ok = (((unsigned)(rv >> 8) & 0xFFFFu) == (unsigned)t); }
            else rv = 0;
            if (__all(ok)) break;
          }
          c_prev = slot_scaled(__shfl(red8(rv), 0, 64));
        }
        // ---- early: hp_c(t) epochs + gather ------------------------------
        {
          const u32* ep = HPEPb + (size_t)par * 28;
          for (;;) {
            u32 v = (lane < 28) ? ld32a(ep + lane) : tg;
            if (__all(v == tg)) break;
          }
        }
        float hpA[3], hpB[3];
        #pragma unroll
        for (int g = 0; g < 3; ++g) {
          hpA[g] = ldf(HPb + (size_t)par * 1344 + g * 448 + u1);
          hpB[g] = hasB ? ldf(HPb + (size_t)par * 1344 + g * 448 + u2) : 0.0f;
        }
        // ---- CRITICAL: f(t-1) slots (tag t) ------------------------------
        if (t >= 1) {
          u64* amf = AMb + (size_t)((2 + parp) * 8) * 8;
          u64 rv = 0;
          for (;;) {
            bool ok = true;
            if (lane < 8) { rv = ld64(amf + lane * 8); ok = (((unsigned)(rv >> 8) & 0xFFFFu) == (unsigned)t); }
            else rv = 0;
            if (__all(ok)) break;
          }
          rvf = __shfl(red8(rv), 0, 64);
          f_prev = slot_scaled(rvf);
          if (oid == 0 && tid == 0) out[TSTEPS + t - 1] = (float)slot_bin(rvf);
        }
        // ---- gates -------------------------------------------------------
        {
          const float p0 = tbA[0] + wiA[0][0] * c_prev + wiA[0][1] * f_prev;
          const float p1 = tbA[1] + wiA[1][0] * c_prev + wiA[1][1] * f_prev;
          const float p2 = tbA[2] + wiA[2][0] * c_prev + wiA[2][1] * f_prev;
          const float r = sigf(p0 + hpA[0]);
          const float u = sigf(p1 + hpA[1]);
          const float n = tanhf(p2 + r * hpA[2]);
          hvA = u * (hvA - n) + n;
          sh[u1] = hvA;
          if (oid == 0) stf(HBUFb + (size_t)par * 896 + u1, hvA);
        }
        if (hasB) {
          const float p0 = tbB[0] + wiB[0][0] * c_prev + wiB[0][1] * f_prev;
          const float p1 = tbB[1] + wiB[1][0] * c_prev + wiB[1][1] * f_prev;
          const float p2 = tbB[2] + wiB[2][0] * c_prev + wiB[2][1] * f_prev;
          const float r = sigf(p0 + hpB[0]);
          const float u = sigf(p1 + hpB[1]);
          const float n = tanhf(p2 + r * hpB[2]);
          hvB = u * (hvB - n) + n;
          sh[u2] = hvB;
          if (oid == 0) stf(HBUFb + (size_t)par * 896 + u2, hvB);
        }
      } else {
        // ---- early: c(t-1), f(t-1) combined (tag t) ----------------------
        if (t >= 1) {
          u64* amc = AMb + (size_t)(parp * 8) * 8;
          u64* amf = AMb + (size_t)((2 + parp) * 8) * 8;
          u64 rv = 0;
          for (;;) {
            bool ok = true;
            if (lane < 8)       { rv = ld64(amc + lane * 8);       ok = (((unsigned)(rv >> 8) & 0xFFFFu) == (unsigned)t); }
            else if (lane < 16) { rv = ld64(amf + (lane - 8) * 8); ok = (((unsigned)(rv >> 8) & 0xFFFFu) == (unsigned)t); }
            else rv = 0;
            if (__all(ok)) break;
          }
          #pragma unroll
          for (int d = 1; d < 8; d <<= 1) rv = u64max(rv, __shfl_xor(rv, d, 64));
          c_prev = slot_scaled(__shfl(rv, 0, 64));
          f_prev = slot_scaled(__shfl(rv, 8, 64));
        }
        // ---- early: hp_f(t) ----------------------------------------------
        {
          const u32* ep = HPEPb + (size_t)(2 + par) * 28;
          for (;;) {
            u32 v = (lane < 28) ? ld32a(ep + lane) : tg;
            if (__all(v == tg)) break;
          }
        }
        float hpA[3], hpB[3];
        #pragma unroll
        for (int g = 0; g < 3; ++g) {
          hpA[g] = ldf(HPb + (size_t)(2 + par) * 1344 + g * 448 + u1);
          hpB[g] = hasB ? ldf(HPb + (size_t)(2 + par) * 1344 + g * 448 + u2) : 0.0f;
        }
        // ---- CRITICAL: coarse AM(t) (tag t+1) ----------------------------
        {
          u64* amc = AMb + (size_t)(par * 8) * 8;
          u64 rv = 0;
          for (;;) {
            bool ok = true;
            if (lane < 8) { rv = ld64(amc + lane * 8); ok = (((unsigned)(rv >> 8) & 0xFFFFu) == tg); }
            else rv = 0;
            if (__all(ok)) break;
          }
          const u64 vc = __shfl(red8(rv), 0, 64);
          csc = slot_scaled(vc);
          if (oid == 0 && tid == 0) out[t] = (float)slot_bin(vc);
        }
        // ---- gates -------------------------------------------------------
        {
          const float p0 = tbA[0] + wiA[0][0] * c_prev + wiA[0][1] * f_prev + wiA[0][2] * csc;
          const float p1 = tbA[1] + wiA[1][0] * c_prev + wiA[1][1] * f_prev + wiA[1][2] * csc;
          const float p2 = tbA[2] + wiA[2][0] * c_prev + wiA[2][1] * f_prev + wiA[2][2] * csc;
          const float r = sigf(p0 + hpA[0]);
          const float u = sigf(p1 + hpA[1]);
          const float n = tanhf(p2 + r * hpA[2]);
          hvA = u * (hvA - n) + n;
          sh[u1] = hvA;
          if (oid == 0) stf(HBUFb + (size_t)par * 896 + 448 + u1, hvA);
        }
        if (hasB) {
          const float p0 = tbB[0] + wiB[0][0] * c_prev + wiB[0][1] * f_prev + wiB[0][2] * csc;
          const float p1 = tbB[1] + wiB[1][0] * c_prev + wiB[1][1] * f_prev + wiB[1][2] * csc;
          const float p2 = tbB[2] + wiB[2][0] * c_prev + wiB[2][1] * f_prev + wiB[2][2] * csc;
          const float r = sigf(p0 + hpB[0]);
          const float u = sigf(p1 + hpB[1]);
          const float n = tanhf(p2 + r * hpB[2]);
          hvB = u * (hvB - n) + n;
          sh[u2] = hvB;
          if (oid == 0) stf(HBUFb + (size_t)par * 896 + 448 + u2, hvB);
        }
      }

      __syncthreads();   // sh[] ready; oid0's global h stores drained
      if (oid == 0 && tid == 0) st32r(HEPb + (size_t)(par * 2 + half) * 16, tg);

      // ---- pre: 14 rows per wave, publish self-tagged ---------------------
      u64* prp = PREb + (size_t)(half * 2 + par) * 448;
      {
        float hv7[7];
        #pragma unroll
        for (int k = 0; k < 7; ++k) hv7[k] = sh[k * 64 + lane];
        #pragma unroll
        for (int r = 0; r < 14; ++r) {
          float s = 0.f;
          #pragma unroll
          for (int k = 0; k < 7; ++k) s = fmaf(wpre[r][k], hv7[k], s);
          s = fmaxf(wave_sum(s) + bpre[r], 0.f);
          if (lane == 0) st64(prp + wl * 14 + r, ((u64)tg << 32) | __float_as_uint(s));
        }
      }
      // ---- poll full pre (self-tagged), bins, publish AM slot -------------
      float pv[7];
      for (;;) {
        u64 v[7]; bool ok = true;
        #pragma unroll
        for (int k = 0; k < 7; ++k) v[k] = ld64(prp + k * 64 + lane);
        #pragma unroll
        for (int k = 0; k < 7; ++k) ok &= ((unsigned)(v[k] >> 32) == tg);
        if (__all(ok)) {
          #pragma unroll
          for (int k = 0; k < 7; ++k) pv[k] = __uint_as_float((unsigned)v[k]);
          break;
        }
      }
      u64 best = 0ull;
      #pragma unroll
      for (int r = 0; r < 8; ++r) {
        float s = 0.f;
        #pragma unroll
        for (int k = 0; k < 7; ++k) s = fmaf(wbin[r][k], pv[k], s);
        s = wave_sum(s) + bbin[r];
        best = u64max(best, pack_key(s, wl * 8 + r, tg));
      }
      if (lane == 0) sm[wv] = best;
      __syncthreads();
      if (tid == 0) {
        const u64 m = u64max(u64max(sm[0], sm[1]), u64max(sm[2], sm[3]));
        st64(AMb + (size_t)((half * 2 + par) * 8 + oid) * 8, m);
      }
    }

    // ---- epilogue -------------------------------------------------------
    if (!half && oid == 0 && tid == 0) {
      u64 m = 0;
      for (int s = 0; s < 8; ++s) {
        u64 v;
        do { v = ld64(AMb + (size_t)((2 + 1) * 8 + s) * 8); }
        while (((unsigned)(v >> 8) & 0xFFFFu) != 16384u);
        m = u64max(m, v);
      }
      out[2 * TSTEPS - 1] = (float)slot_bin(m);
    }
    if (oid == 0) {
      out[2 * TSTEPS + half * 448 + u1] = hvA;
      if (hasB) out[2 * TSTEPS + half * 448 + u2] = hvB;
    }

  } else {
    // =================== hp WGs: coarse 16-43, fine 44-71 ===================
    const int id   = wg - 16;
    const int half = (id >= 28) ? 1 : 0;
    const int wgl  = id - 28 * half;          // 0..27
    const int r0   = (wgl * 4 + wv) * 12;     // first of 12 owned rows

    float wh[12][14], hb[12];
    #pragma unroll
    for (int j = 0; j < 12; ++j) {
      const int grow = half * 1344 + r0 + j;
      #pragma unroll
      for (int k = 0; k < 14; ++k) wh[j][k] = Wh[(size_t)grow * 896 + k * 64 + lane];
      hb[j] = bh[grow];
    }

    for (int t = 0; t < TSTEPS; ++t) {
      const int par = t & 1, parh = par ^ 1;
      float s[12];

      if (t == 0) {
        float hv[14];
        #pragma unroll
        for (int k = 0; k < 14; ++k) hv[k] = h0[k * 64 + lane];
        #pragma unroll
        for (int j = 0; j < 12; ++j) {
          float a = 0.f;
          #pragma unroll
          for (int k = 0; k < 14; ++k) a = fmaf(wh[j][k], hv[k], a);
          s[j] = a;
        }
      } else {
        // coarse half of h(t-1) lands ~3 hops early: start partial sums
        {
          const u32* ep = HEPb + (size_t)(parh * 2 + 0) * 16;
          for (;;) { if (__all(ld32a(ep) == (unsigned)t)) break; }
        }
        float hv[7];
        #pragma unroll
        for (int k = 0; k < 7; ++k) hv[k] = ldf(HBUFb + (size_t)parh * 896 + k * 64 + lane);
        #pragma unroll
        for (int j = 0; j < 12; ++j) {
          float a = 0.f;
          #pragma unroll
          for (int k = 0; k < 7; ++k) a = fmaf(wh[j][k], hv[k], a);
          s[j] = a;
        }
        // fine half
        {
          const u32* ep = HEPb + (size_t)(parh * 2 + 1) * 16;
          for (;;) { if (__all(ld32a(ep) == (unsigned)t)) break; }
        }
        float hw[7];
        #pragma unroll
        for (int k = 0; k < 7; ++k) hw[k] = ldf(HBUFb + (size_t)parh * 896 + (k + 7) * 64 + lane);
        #pragma unroll
        for (int j = 0; j < 12; ++j) {
          float a = s[j];
          #pragma unroll
          for (int k = 0; k < 7; ++k) a = fmaf(wh[j][k + 7], hw[k], a);
          s[j] = a;
        }
      }

      float* hp = HPb + (size_t)(half * 2 + par) * 1344;
      #pragma unroll
      for (int j = 0; j < 12; ++j) {
        const float a = wave_sum(s[j]) + hb[j];
        if (lane == 0) stf(hp + r0 + j, a);
      }
      __syncthreads();
      if (tid == 0) st32r(HPEPb + (size_t)(half * 2 + par) * 28 + wgl, (u32)(t + 1));
    }
  }
}

extern "C" void kernel_launch(void* const* d_in, const int* in_sizes, int n_in,
                              void* d_out, int out_size, void* d_ws, size_t ws_size,
                              hipStream_t stream) {
  (void)in_sizes; (void)n_in; (void)out_size; (void)ws_size;
  wavernn_persist<<<72, 256, 0, stream>>>(
      (const float*)d_in[0],  (const float*)d_in[1],  (const float*)d_in[2],
      (const float*)d_in[3],  (const float*)d_in[4],  (const float*)d_in[5],
      (const float*)d_in[6],  (const float*)d_in[7],  (const float*)d_in[8],
      (const float*)d_in[9],  (const float*)d_in[10], (const float*)d_in[11],
      (const float*)d_in[12], (const float*)d_in[13], (const float*)d_in[14],
      (float*)d_out, (char*)d_ws);
}

// Round 4
// 222733.618 us; speedup vs baseline: 1.5894x; 1.5894x over previous
//
#include <hip/hip_runtime.h>

#define AGENT __HIP_MEMORY_SCOPE_AGENT
typedef unsigned int u32;
typedef unsigned long long u64;

constexpr int TSTEPS = 16384;
constexpr float INV_BINS    = 1.0f / 127.5f;
constexpr float INIT_SCALED = 128.0f * (1.0f / 127.5f) - 1.0f;

// ---- workspace byte offsets ------------------------------------------------
constexpr int AM_OFF   = 0;      // u64 slots: ((half*2+par)*16 + s) * 64B       -> 4 KiB
constexpr int HEP_OFF  = 4096;   // u32 x8 copies: ((par*2+half)*8 + c) * 64B    -> 2 KiB
constexpr int HPEP_OFF = 6144;   // u32: (half*2+par)*64 + wgl                   -> 1 KiB
constexpr int HBUF_OFF = 7168;   // f32: par*896 + i                             -> 7 KiB
constexpr int HP_OFF   = 14336;  // f32: (half*2+par)*1344 + i                   -> 21 KiB
constexpr int PRE_OFF  = 35840;  // u64 tagged: (half*2+par)*448 + i             -> end 50176

__device__ __forceinline__ u32  ld32(const u32* p) { return __hip_atomic_load((u32*)p, __ATOMIC_RELAXED, AGENT); }
__device__ __forceinline__ void st32r(u32* p, u32 v){ __hip_atomic_store(p, v, __ATOMIC_RELEASE, AGENT); }
__device__ __forceinline__ float ldf(const float* p){ return __hip_atomic_load((float*)p, __ATOMIC_RELAXED, AGENT); }
__device__ __forceinline__ void  stf(float* p, float v){ __hip_atomic_store(p, v, __ATOMIC_RELAXED, AGENT); }
__device__ __forceinline__ u64  ld64(const u64* p){ return __hip_atomic_load((u64*)p, __ATOMIC_RELAXED, AGENT); }
__device__ __forceinline__ void st64(u64* p, u64 v){ __hip_atomic_store(p, v, __ATOMIC_RELAXED, AGENT); }

__device__ __forceinline__ float wave_sum(float s) {
  #pragma unroll
  for (int d = 1; d < 64; d <<= 1) s += __shfl_xor(s, d, 64);
  return s;
}
__device__ __forceinline__ float sigf(float x) { return 1.0f / (1.0f + __expf(-x)); }
__device__ __forceinline__ u64 u64max(u64 a, u64 b) { return a > b ? a : b; }
__device__ __forceinline__ u64 red16(u64 v) {
  #pragma unroll
  for (int d = 1; d < 16; d <<= 1) v = u64max(v, __shfl_xor(v, d, 64));
  return v;
}
// packed argmax slot: [key:32 | tag:16 | 255-row:8]
__device__ __forceinline__ u64 pack_key(float x, int row, unsigned tag) {
  unsigned u = __float_as_uint(x);
  u = (u & 0x80000000u) ? ~u : (u | 0x80000000u);
  return ((u64)u << 32) | ((u64)(tag & 0xFFFFu) << 8) | (unsigned)(255 - row);
}
__device__ __forceinline__ int   slot_bin(u64 v)    { return 255 - (int)(v & 0xFFull); }
__device__ __forceinline__ float slot_scaled(u64 v) { return (float)slot_bin(v) * INV_BINS - 1.0f; }

extern "C" __global__ void __launch_bounds__(256, 1)
wavernn_persist(const float* __restrict__ Wh,  const float* __restrict__ bh,
                const float* __restrict__ Wci, const float* __restrict__ Wfi,
                const float* __restrict__ cbias, const float* __restrict__ fbias,
                const float* __restrict__ pWc, const float* __restrict__ pBc,
                const float* __restrict__ bWc, const float* __restrict__ bBc,
                const float* __restrict__ pWf, const float* __restrict__ pBf,
                const float* __restrict__ bWf, const float* __restrict__ bBf,
                const float* __restrict__ h0,
                float* __restrict__ out, char* __restrict__ wsb)
{
  const int tid  = threadIdx.x;
  const int lane = tid & 63;
  const int wv   = tid >> 6;
  const int wg   = blockIdx.x;

  u64* AMb    = (u64*)(wsb + AM_OFF);
  u32* HEPb   = (u32*)(wsb + HEP_OFF);
  u32* HPEPb  = (u32*)(wsb + HPEP_OFF);
  float* HBUFb = (float*)(wsb + HBUF_OFF);
  float* HPb   = (float*)(wsb + HP_OFF);
  u64* PREb    = (u64*)(wsb + PRE_OFF);

  if (wg < 32) {
    // ============ output WGs: coarse 0-15, fine 16-31 =======================
    const int half = wg >> 4;
    const int oid  = wg & 15;
    const int ncol = half ? 3 : 2;
    const float* Wi  = half ? Wfi : Wci;
    const float* tbp = half ? fbias : cbias;
    const float* pW  = half ? pWf : pWc;
    const float* pB  = half ? pBf : pBc;
    const float* bW  = half ? bWf : bWc;
    const float* bB  = half ? bBf : bBc;

    const int u1 = tid;                 // gate unit 1 (0..255)
    const bool hasB = (tid < 192);
    const int u2 = 256 + tid;           // gate unit 2 (256..447)

    float wiA[3][3], wiB[3][3];
    #pragma unroll
    for (int g = 0; g < 3; ++g)
      #pragma unroll
      for (int c = 0; c < 3; ++c) {
        wiA[g][c] = (c < ncol) ? Wi[(g * 448 + u1) * ncol + c] : 0.0f;
        wiB[g][c] = (hasB && c < ncol) ? Wi[(g * 448 + u2) * ncol + c] : 0.0f;
      }
    float hvA = h0[half * 448 + u1];
    float hvB = hasB ? h0[half * 448 + u2] : 0.0f;

    const int wl = oid * 4 + wv;        // 0..63
    float wpre[7][7], bpre[7], wbin[4][7], bbin[4];
    #pragma unroll
    for (int r = 0; r < 7; ++r) {
      const int row = wl * 7 + r;       // 448 pre rows
      #pragma unroll
      for (int k = 0; k < 7; ++k) wpre[r][k] = pW[row * 448 + k * 64 + lane];
      bpre[r] = pB[row];
    }
    #pragma unroll
    for (int r = 0; r < 4; ++r) {
      const int row = wl * 4 + r;       // 256 bin rows
      #pragma unroll
      for (int k = 0; k < 7; ++k) wbin[r][k] = bW[row * 448 + k * 64 + lane];
      bbin[r] = bB[row];
    }

    __shared__ float sh[448];
    __shared__ u64 sm[4];
    __shared__ u64 sU[3];
    __shared__ float sF[2];

    for (int t = 0; t < TSTEPS; ++t) {
      const int par = t & 1, parp = par ^ 1;
      const unsigned tg = (unsigned)(t + 1);

      // per-step bias prefetch (HBM latency hides under the polls)
      float tbA[3], tbB[3];
      #pragma unroll
      for (int g = 0; g < 3; ++g) {
        tbA[g] = tbp[(size_t)t * 1344 + g * 448 + u1];
        tbB[g] = hasB ? tbp[(size_t)t * 1344 + g * 448 + u2] : 0.0f;
      }

      if (!half) {
        // ---- wave0: early poll c(t-1) + hp_c ready ----------------------
        if (wv == 0) {
          if (t >= 1) {
            u64* amc = AMb + (size_t)(parp * 16) * 8;
            u64 rv = 0;
            for (;;) {
              bool ok = true;
              if (lane < 16) { rv = ld64(amc + lane * 8); ok = (((unsigned)(rv >> 8) & 0xFFFFu) == (unsigned)t); }
              else rv = 0;
              if (__all(ok)) break;
            }
            rv = red16(rv);
            if (lane == 0) sF[0] = slot_scaled(rv);
          } else if (lane == 0) sF[0] = INIT_SCALED;
          const u32* ep = HPEPb + (size_t)par * 64;
          for (;;) {
            u32 v = (lane < 42) ? ld32(ep + lane) : tg;
            if (__all(v == tg)) break;
            __builtin_amdgcn_s_sleep(1);
          }
        }
        __syncthreads();                                   // B1
        const float c_prev = sF[0];
        float hpA[3], hpB[3], pA[3], pB3[3];
        #pragma unroll
        for (int g = 0; g < 3; ++g) {
          hpA[g] = ldf(HPb + (size_t)par * 1344 + g * 448 + u1);
          hpB[g] = hasB ? ldf(HPb + (size_t)par * 1344 + g * 448 + u2) : 0.0f;
          pA[g]  = fmaf(wiA[g][0], c_prev, tbA[g]);
          pB3[g] = fmaf(wiB[g][0], c_prev, tbB[g]);
        }
        // ---- wave0: CRITICAL poll f(t-1) --------------------------------
        if (wv == 0) {
          if (t >= 1) {
            u64* amf = AMb + (size_t)((2 + parp) * 16) * 8;
            u64 rv = 0;
            for (;;) {
              bool ok = true;
              if (lane < 16) { rv = ld64(amf + lane * 8); ok = (((unsigned)(rv >> 8) & 0xFFFFu) == (unsigned)t); }
              else rv = 0;
              if (__all(ok)) break;
            }
            rv = red16(rv);
            if (lane == 0) sU[0] = rv;
          } else if (lane == 0) sU[0] = 0;
        }
        __syncthreads();                                   // B2
        const float f_prev = (t >= 1) ? slot_scaled(sU[0]) : INIT_SCALED;
        {
          const float p0 = fmaf(wiA[0][1], f_prev, pA[0]);
          const float p1 = fmaf(wiA[1][1], f_prev, pA[1]);
          const float p2 = fmaf(wiA[2][1], f_prev, pA[2]);
          const float r = sigf(p0 + hpA[0]);
          const float u = sigf(p1 + hpA[1]);
          const float n = tanhf(p2 + r * hpA[2]);
          hvA = u * (hvA - n) + n;
          sh[u1] = hvA;
          if (oid == 0) stf(HBUFb + (size_t)par * 896 + u1, hvA);
        }
        if (hasB) {
          const float p0 = fmaf(wiB[0][1], f_prev, pB3[0]);
          const float p1 = fmaf(wiB[1][1], f_prev, pB3[1]);
          const float p2 = fmaf(wiB[2][1], f_prev, pB3[2]);
          const float r = sigf(p0 + hpB[0]);
          const float u = sigf(p1 + hpB[1]);
          const float n = tanhf(p2 + r * hpB[2]);
          hvB = u * (hvB - n) + n;
          sh[u2] = hvB;
          if (oid == 0) stf(HBUFb + (size_t)par * 896 + u2, hvB);
        }
        __syncthreads();                                   // B3 (drains h stores)
        if (oid == 0 && tid < 8) st32r(HEPb + (size_t)((par * 2 + 0) * 8 + tid) * 16, tg);
        if (oid == 0 && tid == 0 && t >= 1) out[TSTEPS + t - 1] = (float)slot_bin(sU[0]);
      } else {
        // ---- fine: wave0 early poll c(t-1)+f(t-1) + hp_f ready ----------
        if (wv == 0) {
          if (t >= 1) {
            u64* amc = AMb + (size_t)(parp * 16) * 8;
            u64* amf = AMb + (size_t)((2 + parp) * 16) * 8;
            u64 rv = 0;
            for (;;) {
              bool ok = true;
              if (lane < 16)      { rv = ld64(amc + lane * 8);        ok = (((unsigned)(rv >> 8) & 0xFFFFu) == (unsigned)t); }
              else if (lane < 32) { rv = ld64(amf + (lane - 16) * 8); ok = (((unsigned)(rv >> 8) & 0xFFFFu) == (unsigned)t); }
              else rv = 0;
              if (__all(ok)) break;
            }
            rv = red16(rv);
            const u64 vf = __shfl(rv, 16, 64);
            if (lane == 0) { sF[0] = slot_scaled(rv); sF[1] = slot_scaled(vf); }
          } else if (lane == 0) { sF[0] = INIT_SCALED; sF[1] = INIT_SCALED; }
          const u32* ep = HPEPb + (size_t)(2 + par) * 64;
          for (;;) {
            u32 v = (lane < 42) ? ld32(ep + lane) : tg;
            if (__all(v == tg)) break;
            __builtin_amdgcn_s_sleep(1);
          }
        }
        __syncthreads();                                   // B1
        const float c_prev = sF[0], f_prev = sF[1];
        float hpA[3], hpB[3], linA[3], linB[3];
        #pragma unroll
        for (int g = 0; g < 3; ++g) {
          hpA[g] = ldf(HPb + (size_t)(2 + par) * 1344 + g * 448 + u1);
          hpB[g] = hasB ? ldf(HPb + (size_t)(2 + par) * 1344 + g * 448 + u2) : 0.0f;
          linA[g] = fmaf(wiA[g][1], f_prev, fmaf(wiA[g][0], c_prev, tbA[g]));
          linB[g] = fmaf(wiB[g][1], f_prev, fmaf(wiB[g][0], c_prev, tbB[g]));
        }
        // ---- wave0: CRITICAL poll coarse AM(t) --------------------------
        if (wv == 0) {
          u64* amc = AMb + (size_t)(par * 16) * 8;
          u64 rv = 0;
          for (;;) {
            bool ok = true;
            if (lane < 16) { rv = ld64(amc + lane * 8); ok = (((unsigned)(rv >> 8) & 0xFFFFu) == tg); }
            else rv = 0;
            if (__all(ok)) break;
          }
          rv = red16(rv);
          if (lane == 0) sU[2] = rv;
        }
        __syncthreads();                                   // B2
        const u64 vc = sU[2];
        const float csc = slot_scaled(vc);
        {
          const float p0 = fmaf(wiA[0][2], csc, linA[0]);
          const float p1 = fmaf(wiA[1][2], csc, linA[1]);
          const float p2 = fmaf(wiA[2][2], csc, linA[2]);
          const float r = sigf(p0 + hpA[0]);
          const float u = sigf(p1 + hpA[1]);
          const float n = tanhf(p2 + r * hpA[2]);
          hvA = u * (hvA - n) + n;
          sh[u1] = hvA;
          if (oid == 0) stf(HBUFb + (size_t)par * 896 + 448 + u1, hvA);
        }
        if (hasB) {
          const float p0 = fmaf(wiB[0][2], csc, linB[0]);
          const float p1 = fmaf(wiB[1][2], csc, linB[1]);
          const float p2 = fmaf(wiB[2][2], csc, linB[2]);
          const float r = sigf(p0 + hpB[0]);
          const float u = sigf(p1 + hpB[1]);
          const float n = tanhf(p2 + r * hpB[2]);
          hvB = u * (hvB - n) + n;
          sh[u2] = hvB;
          if (oid == 0) stf(HBUFb + (size_t)par * 896 + 448 + u2, hvB);
        }
        __syncthreads();                                   // B3
        if (oid == 0 && tid < 8) st32r(HEPb + (size_t)((par * 2 + 1) * 8 + tid) * 16, tg);
        if (oid == 0 && tid == 0) out[t] = (float)slot_bin(vc);
      }

      // ---- pre: 7 rows per wave, publish self-tagged ----------------------
      u64* prp = PREb + (size_t)(half * 2 + par) * 448;
      {
        float hv7[7];
        #pragma unroll
        for (int k = 0; k < 7; ++k) hv7[k] = sh[k * 64 + lane];
        #pragma unroll
        for (int r = 0; r < 7; ++r) {
          float s = 0.f;
          #pragma unroll
          for (int k = 0; k < 7; ++k) s = fmaf(wpre[r][k], hv7[k], s);
          s = fmaxf(wave_sum(s) + bpre[r], 0.f);
          if (lane == 0) st64(prp + wl * 7 + r, ((u64)tg << 32) | __float_as_uint(s));
        }
      }
      // ---- poll full pre (self-tagged), bins, publish AM partial ----------
      float pv[7];
      for (;;) {
        u64 v[7]; bool ok = true;
        #pragma unroll
        for (int k = 0; k < 7; ++k) v[k] = ld64(prp + k * 64 + lane);
        #pragma unroll
        for (int k = 0; k < 7; ++k) ok &= ((unsigned)(v[k] >> 32) == tg);
        if (__all(ok)) {
          #pragma unroll
          for (int k = 0; k < 7; ++k) pv[k] = __uint_as_float((unsigned)v[k]);
          break;
        }
      }
      u64 best = 0ull;
      #pragma unroll
      for (int r = 0; r < 4; ++r) {
        float s = 0.f;
        #pragma unroll
        for (int k = 0; k < 7; ++k) s = fmaf(wbin[r][k], pv[k], s);
        s = wave_sum(s) + bbin[r];
        best = u64max(best, pack_key(s, wl * 4 + r, tg));
      }
      if (lane == 0) sm[wv] = best;
      __syncthreads();                                     // B4
      if (tid == 0) {
        const u64 m = u64max(u64max(sm[0], sm[1]), u64max(sm[2], sm[3]));
        st64(AMb + (size_t)((half * 2 + par) * 16 + oid) * 8, m);
      }
    }

    // ---- epilogue --------------------------------------------------------
    if (!half && oid == 0 && tid == 0) {
      u64 m = 0;
      for (int s = 0; s < 16; ++s) {
        u64 v;
        do { v = ld64(AMb + (size_t)(3 * 16 + s) * 8); }
        while (((unsigned)(v >> 8) & 0xFFFFu) != 16384u);
        m = u64max(m, v);
      }
      out[2 * TSTEPS - 1] = (float)slot_bin(m);
    }
    if (oid == 0) {
      out[2 * TSTEPS + half * 448 + u1] = hvA;
      if (hasB) out[2 * TSTEPS + half * 448 + u2] = hvB;
    }

  } else {
    // =================== hp WGs: coarse 32-73, fine 74-115 ==================
    const int id   = wg - 32;
    const int half = (id >= 42) ? 1 : 0;
    const int wgl  = id - 42 * half;          // 0..41
    const int r0   = (wgl * 4 + wv) * 8;      // first of 8 owned rows
    const int cp   = wg & 7;                  // HEP replica to poll

    float wh[8][14], hb[8];
    #pragma unroll
    for (int j = 0; j < 8; ++j) {
      const int grow = half * 1344 + r0 + j;
      #pragma unroll
      for (int k = 0; k < 14; ++k) wh[j][k] = Wh[(size_t)grow * 896 + k * 64 + lane];
      hb[j] = bh[grow];
    }

    for (int t = 0; t < TSTEPS; ++t) {
      const int par = t & 1, parh = par ^ 1;
      float s[8];

      if (t == 0) {
        float hv[14];
        #pragma unroll
        for (int k = 0; k < 14; ++k) hv[k] = h0[k * 64 + lane];
        #pragma unroll
        for (int j = 0; j < 8; ++j) {
          float a = 0.f;
          #pragma unroll
          for (int k = 0; k < 14; ++k) a = fmaf(wh[j][k], hv[k], a);
          s[j] = a;
        }
      } else {
        // coarse half of h(t-1) lands early: partial sums first
        if (wv == 0) {
          const u32* ep = HEPb + (size_t)((parh * 2 + 0) * 8 + cp) * 16;
          for (;;) {
            u32 v = 0;
            if (lane == 0) v = ld32(ep);
            if (__shfl(v, 0, 64) == (unsigned)t) break;
            __builtin_amdgcn_s_sleep(1);
          }
        }
        __syncthreads();
        float hv[7];
        #pragma unroll
        for (int k = 0; k < 7; ++k) hv[k] = ldf(HBUFb + (size_t)parh * 896 + k * 64 + lane);
        #pragma unroll
        for (int j = 0; j < 8; ++j) {
          float a = 0.f;
          #pragma unroll
          for (int k = 0; k < 7; ++k) a = fmaf(wh[j][k], hv[k], a);
          s[j] = a;
        }
        if (wv == 0) {
          const u32* ep = HEPb + (size_t)((parh * 2 + 1) * 8 + cp) * 16;
          for (;;) {
            u32 v = 0;
            if (lane == 0) v = ld32(ep);
            if (__shfl(v, 0, 64) == (unsigned)t) break;
            __builtin_amdgcn_s_sleep(1);
          }
        }
        __syncthreads();
        float hw[7];
        #pragma unroll
        for (int k = 0; k < 7; ++k) hw[k] = ldf(HBUFb + (size_t)parh * 896 + (k + 7) * 64 + lane);
        #pragma unroll
        for (int j = 0; j < 8; ++j) {
          float a = s[j];
          #pragma unroll
          for (int k = 0; k < 7; ++k) a = fmaf(wh[j][k + 7], hw[k], a);
          s[j] = a;
        }
      }

      float* hp = HPb + (size_t)(half * 2 + par) * 1344;
      #pragma unroll
      for (int j = 0; j < 8; ++j) {
        const float a = wave_sum(s[j]) + hb[j];
        if (lane == 0) stf(hp + r0 + j, a);
      }
      __syncthreads();   // drains hp stores (vmcnt(0) at barrier)
      if (tid == 0) st32r(HPEPb + (size_t)(half * 2 + par) * 64 + wgl, (u32)(t + 1));
    }
  }
}

extern "C" void kernel_launch(void* const* d_in, const int* in_sizes, int n_in,
                              void* d_out, int out_size, void* d_ws, size_t ws_size,
                              hipStream_t stream) {
  (void)in_sizes; (void)n_in; (void)out_size; (void)ws_size;
  wavernn_persist<<<116, 256, 0, stream>>>(
      (const float*)d_in[0],  (const float*)d_in[1],  (const float*)d_in[2],
      (const float*)d_in[3],  (const float*)d_in[4],  (const float*)d_in[5],
      (const float*)d_in[6],  (const float*)d_in[7],  (const float*)d_in[8],
      (const float*)d_in[9],  (const float*)d_in[10], (const float*)d_in[11],
      (const float*)d_in[12], (const float*)d_in[13], (const float*)d_in[14],
      (float*)d_out, (char*)d_ws);
}